// Round 7
// baseline (272.902 us; speedup 1.0000x reference)
//
#include <hip/hip_runtime.h>
#include <math.h>

#define BB 32
#define SS 4096
#define DD 256
#define DAA 128
#define DPP 64
#define CHUNKS 32
#define ROWS_PER_BLOCK (SS / CHUNKS)                     // 128
#define WAVES_PER_BLOCK 4
#define ROWS_PER_WAVE (ROWS_PER_BLOCK / WAVES_PER_BLOCK) // 32
#define BATCH 4
#define NBATCH (ROWS_PER_WAVE / BATCH)                   // 8
#define VH_SLICES 8
#define SLICE (DAA / VH_SLICES)                          // 16

// workspace layout (float elements)
#define WS_VHP  0                         // 8 x 256 partial vh
#define WS_VQP  (WS_VHP + VH_SLICES*DD)   // 8 x 256 partial vq
#define WS_VP   (WS_VQP + VH_SLICES*DD)   // 128: [vp1[64] | vp2[64]]
#define WS_BC   (WS_VP + 128)
#define WS_PART (WS_BC + 16)              // 16B-aligned
#define PART_STRIDE 258                   // [l, ctx[256], pad]

typedef float f4 __attribute__((ext_vector_type(4)));
typedef float f2 __attribute__((ext_vector_type(2)));

// ---------------------------------------------------------------------------
// Kernel 0: fold Wc into projection vectors. Blocks 0..7 each do a 16-row
// slice of the Wh/Wq dots; block 8 does vp1/vp2/bc. main sums the 8
// partials per lane.
// ---------------------------------------------------------------------------
__global__ void prep_kernel(const float* __restrict__ Wh,
                            const float* __restrict__ Wq,
                            const float* __restrict__ Wp1,
                            const float* __restrict__ Wp2,
                            const float* __restrict__ Wc,
                            const float* __restrict__ bc,
                            float* __restrict__ ws) {
    const int tid = threadIdx.x; // 256 threads
    const int blk = blockIdx.x;
    if (blk < VH_SLICES) {
        const int a0 = blk * SLICE;
        float vh = 0.f, vq = 0.f;
        #pragma unroll
        for (int i = 0; i < SLICE; ++i) {
            const int a = a0 + i;
            vh += Wh[a * DD + tid] * Wc[a];
            vq += Wq[a * DD + tid] * Wc[DAA + a];
        }
        ws[WS_VHP + blk * DD + tid] = vh;
        ws[WS_VQP + blk * DD + tid] = vq;
    } else {
        if (tid < DPP) {
            float vp1 = 0.f, vp2 = 0.f;
            for (int a = 0; a < DPP; ++a) {
                vp1 += Wp1[a * DPP + tid] * Wc[2 * DAA + a];
                vp2 += Wp2[a * DPP + tid] * Wc[2 * DAA + DPP + a];
            }
            ws[WS_VP + tid]       = vp1;   // lanes 0..31 read pairs from here
            ws[WS_VP + DPP + tid] = vp2;   // lanes 32..63 read pairs from here
        }
        if (tid == 0) ws[WS_BC] = bc[0];
    }
}

// ---------------------------------------------------------------------------
// Kernel 1: streaming tanh-softmax context.
// R12: ROOT CAUSE of R2/R3/R5/R6 spills: __launch_bounds__'s 2nd arg is a
// MINIMUM waves/EU -- the AMDGPU allocator still TARGETS max occupancy
// (8 waves/EU here), caps VGPRs at 512/8=64, and spills the dbuf state
// (every build, any source form, reported VGPR_Count=64). Fix:
// amdgpu_waves_per_eu(4,4) sets the MAX too -> 128-VGPR budget, no spill.
// Zero real-occupancy cost: grid 1024 = 4 blocks/CU = 4 waves/EU exactly;
// the HW could never run >4 waves/EU with this grid anyway.
// Structure = R6: BATCH=4 double-buffer in named SSA scalars (48 buffer
// VGPRs, ~90 peak live), macros expand to straight-line code.
// Bulk reads nontemporal (drain shielding). No __threadfence.
// ---------------------------------------------------------------------------
#define LOAD4(H0, H1, H2, H3, P0, P1, P2, P3, IB)                              \
    H0 = __builtin_nontemporal_load(hbase + (size_t)(s0 + (IB)*BATCH + 0) * (DD/4) + lane); \
    P0 = __builtin_nontemporal_load((const f2*)(pfsel + (size_t)(s0 + (IB)*BATCH + 0) * DPP)); \
    H1 = __builtin_nontemporal_load(hbase + (size_t)(s0 + (IB)*BATCH + 1) * (DD/4) + lane); \
    P1 = __builtin_nontemporal_load((const f2*)(pfsel + (size_t)(s0 + (IB)*BATCH + 1) * DPP)); \
    H2 = __builtin_nontemporal_load(hbase + (size_t)(s0 + (IB)*BATCH + 2) * (DD/4) + lane); \
    P2 = __builtin_nontemporal_load((const f2*)(pfsel + (size_t)(s0 + (IB)*BATCH + 2) * DPP)); \
    H3 = __builtin_nontemporal_load(hbase + (size_t)(s0 + (IB)*BATCH + 3) * (DD/4) + lane); \
    P3 = __builtin_nontemporal_load((const f2*)(pfsel + (size_t)(s0 + (IB)*BATCH + 3) * DPP));

#define DOT(H, P) ((H).x * vh4.x + (H).y * vh4.y + (H).z * vh4.z + (H).w * vh4.w \
                 + (P).x * vpl.x + (P).y * vpl.y)

#define BFLY(OFF)                                                              \
    r0 += __shfl_xor(r0, OFF, 64);                                             \
    r1 += __shfl_xor(r1, OFF, 64);                                             \
    r2 += __shfl_xor(r2, OFF, 64);                                             \
    r3 += __shfl_xor(r3, OFF, 64);

#define FIN(H, R)                                                              \
    {                                                                          \
        const float score_ = (R) + qd;                                         \
        const float e2_ = __expf(2.f * score_);                                \
        const float t_  = 1.f - 2.f * __builtin_amdgcn_rcpf(e2_ + 1.f);        \
        const float w_  = __expf(t_);                                          \
        l += w_;                                                               \
        ctx.x += w_ * (H).x;                                                   \
        ctx.y += w_ * (H).y;                                                   \
        ctx.z += w_ * (H).z;                                                   \
        ctx.w += w_ * (H).w;                                                   \
    }

#define COMPUTE4(H0, H1, H2, H3, P0, P1, P2, P3)                               \
    {                                                                          \
        float r0 = DOT(H0, P0);                                                \
        float r1 = DOT(H1, P1);                                                \
        float r2 = DOT(H2, P2);                                                \
        float r3 = DOT(H3, P3);                                                \
        BFLY(32) BFLY(16) BFLY(8) BFLY(4) BFLY(2) BFLY(1)                      \
        FIN(H0, r0) FIN(H1, r1) FIN(H2, r2) FIN(H3, r3)                        \
    }

__global__ __launch_bounds__(256) __attribute__((amdgpu_waves_per_eu(4, 4))) void
main_kernel(const float* __restrict__ h,
            const float* __restrict__ q,
            const float* __restrict__ pf1,
            const float* __restrict__ pf2,
            float* __restrict__ ws) {
    const int c    = blockIdx.x;
    const int b    = blockIdx.y;
    const int tid  = threadIdx.x;
    const int wave = tid >> 6;
    const int lane = tid & 63;
    const int ll   = lane & 31;

    // per-lane constants: sum the 8 prep partials (L2-hot)
    f4 vh4 = {0.f, 0.f, 0.f, 0.f};
    f4 vq4 = {0.f, 0.f, 0.f, 0.f};
    #pragma unroll
    for (int k = 0; k < VH_SLICES; ++k) {
        vh4 += ((const f4*)(ws + WS_VHP + k * DD))[lane];
        vq4 += ((const f4*)(ws + WS_VQP + k * DD))[lane];
    }
    const f2 vpl = ((const f2*)(ws + WS_VP))[lane];

    // per-batch q scalar, computed redundantly per wave (cached reads)
    const float4 q4 = ((const float4*)(q + (size_t)b * DD))[lane];
    float qp = q4.x * vq4.x + q4.y * vq4.y + q4.z * vq4.z + q4.w * vq4.w;
    #pragma unroll
    for (int off = 32; off >= 1; off >>= 1) qp += __shfl_xor(qp, off, 64);
    const float qd = qp + ws[WS_BC];

    const int s0 = c * ROWS_PER_BLOCK + wave * ROWS_PER_WAVE;
    const f4*    hbase = (const f4*)(h + (size_t)b * SS * DD);
    const float* pfsel = ((lane < 32) ? pf1 : pf2) + (size_t)b * SS * DPP + 2 * ll;

    float  l = 0.f;
    float4 ctx = make_float4(0.f, 0.f, 0.f, 0.f);

    // double-buffered pipeline over NBATCH=8, all state in named SSA vars
    f4 hA0, hA1, hA2, hA3, hB0, hB1, hB2, hB3;
    f2 pA0, pA1, pA2, pA3, pB0, pB1, pB2, pB3;

    LOAD4(hA0, hA1, hA2, hA3, pA0, pA1, pA2, pA3, 0)
    LOAD4(hB0, hB1, hB2, hB3, pB0, pB1, pB2, pB3, 1)
    COMPUTE4(hA0, hA1, hA2, hA3, pA0, pA1, pA2, pA3)
    LOAD4(hA0, hA1, hA2, hA3, pA0, pA1, pA2, pA3, 2)
    COMPUTE4(hB0, hB1, hB2, hB3, pB0, pB1, pB2, pB3)
    LOAD4(hB0, hB1, hB2, hB3, pB0, pB1, pB2, pB3, 3)
    COMPUTE4(hA0, hA1, hA2, hA3, pA0, pA1, pA2, pA3)
    LOAD4(hA0, hA1, hA2, hA3, pA0, pA1, pA2, pA3, 4)
    COMPUTE4(hB0, hB1, hB2, hB3, pB0, pB1, pB2, pB3)
    LOAD4(hB0, hB1, hB2, hB3, pB0, pB1, pB2, pB3, 5)
    COMPUTE4(hA0, hA1, hA2, hA3, pA0, pA1, pA2, pA3)
    LOAD4(hA0, hA1, hA2, hA3, pA0, pA1, pA2, pA3, 6)
    COMPUTE4(hB0, hB1, hB2, hB3, pB0, pB1, pB2, pB3)
    LOAD4(hB0, hB1, hB2, hB3, pB0, pB1, pB2, pB3, 7)
    COMPUTE4(hA0, hA1, hA2, hA3, pA0, pA1, pA2, pA3)
    COMPUTE4(hB0, hB1, hB2, hB3, pB0, pB1, pB2, pB3)

    // combine the block's 4 waves in LDS, then one plain store per thread
    __shared__ float s_l[WAVES_PER_BLOCK];
    __shared__ float s_ctx[WAVES_PER_BLOCK][DD];
    if (lane == 0) s_l[wave] = l;
    ((float4*)s_ctx[wave])[lane] = ctx;
    __syncthreads();

    const float cd = s_ctx[0][tid] + s_ctx[1][tid] + s_ctx[2][tid] + s_ctx[3][tid];
    float* part_out = ws + WS_PART + (size_t)(b * CHUNKS + c) * PART_STRIDE;
    part_out[1 + tid] = cd;
    if (tid == 0) part_out[0] = s_l[0] + s_l[1] + s_l[2] + s_l[3];
}

// ---------------------------------------------------------------------------
// Kernel 2: merge the CHUNKS partials per batch, scale by 1/(L*S).
// ---------------------------------------------------------------------------
__global__ void finalize_kernel(const float* __restrict__ ws,
                                float* __restrict__ out) {
    const int b   = blockIdx.x;
    const int tid = threadIdx.x; // 256
    __shared__ float s_l[CHUNKS];
    const float* base = ws + WS_PART + (size_t)b * CHUNKS * PART_STRIDE;
    if (tid < CHUNKS) s_l[tid] = base[(size_t)tid * PART_STRIDE];
    __syncthreads();
    float L = 0.f, acc = 0.f;
    #pragma unroll 8
    for (int c = 0; c < CHUNKS; ++c) {
        L   += s_l[c];
        acc += base[(size_t)c * PART_STRIDE + 1 + tid];
    }
    out[b * DD + tid] = acc / (L * (float)SS);
}

extern "C" void kernel_launch(void* const* d_in, const int* in_sizes, int n_in,
                              void* d_out, int out_size, void* d_ws, size_t ws_size,
                              hipStream_t stream) {
    const float* h   = (const float*)d_in[0];
    const float* q   = (const float*)d_in[1];
    const float* pf1 = (const float*)d_in[2];
    const float* pf2 = (const float*)d_in[3];
    const float* Wh  = (const float*)d_in[4];
    const float* Wq  = (const float*)d_in[5];
    const float* Wp1 = (const float*)d_in[6];
    const float* Wp2 = (const float*)d_in[7];
    const float* Wc  = (const float*)d_in[8];
    const float* bc  = (const float*)d_in[9];
    float* out = (float*)d_out;
    float* ws  = (float*)d_ws;

    prep_kernel<<<VH_SLICES + 1, 256, 0, stream>>>(Wh, Wq, Wp1, Wp2, Wc, bc, ws);
    main_kernel<<<dim3(CHUNKS, BB), 256, 0, stream>>>(h, q, pf1, pf2, ws);
    finalize_kernel<<<BB, 256, 0, stream>>>(ws, out);
}

// Round 8
// 241.121 us; speedup vs baseline: 1.1318x; 1.1318x over previous
//
#include <hip/hip_runtime.h>
#include <math.h>

#define BB 32
#define SS 4096
#define DD 256
#define DAA 128
#define DPP 64
#define CHUNKS 32
#define ROWS_PER_BLOCK (SS / CHUNKS)                     // 128
#define WAVES_PER_BLOCK 4
#define ROWS_PER_WAVE (ROWS_PER_BLOCK / WAVES_PER_BLOCK) // 32
#define BATCH 8
#define NBATCH (ROWS_PER_WAVE / BATCH)                   // 4
#define VH_SLICES 8
#define SLICE (DAA / VH_SLICES)                          // 16

// workspace layout (float elements)
#define WS_VHP  0                         // 8 x 256 partial vh
#define WS_VQP  (WS_VHP + VH_SLICES*DD)   // 8 x 256 partial vq
#define WS_VP   (WS_VQP + VH_SLICES*DD)   // 128: [vp1[64] | vp2[64]]
#define WS_BC   (WS_VP + 128)
#define WS_PART (WS_BC + 16)              // 16B-aligned
#define PART_STRIDE 258                   // [l, ctx[256], pad]

typedef float f4 __attribute__((ext_vector_type(4)));
typedef float f2 __attribute__((ext_vector_type(2)));

// ---------------------------------------------------------------------------
// Kernel 0: fold Wc into projection vectors. Blocks 0..7 each do a 16-row
// slice of the Wh/Wq dots; block 8 does vp1/vp2/bc. main sums the 8
// partials per lane.
// ---------------------------------------------------------------------------
__global__ void prep_kernel(const float* __restrict__ Wh,
                            const float* __restrict__ Wq,
                            const float* __restrict__ Wp1,
                            const float* __restrict__ Wp2,
                            const float* __restrict__ Wc,
                            const float* __restrict__ bc,
                            float* __restrict__ ws) {
    const int tid = threadIdx.x; // 256 threads
    const int blk = blockIdx.x;
    if (blk < VH_SLICES) {
        const int a0 = blk * SLICE;
        float vh = 0.f, vq = 0.f;
        #pragma unroll
        for (int i = 0; i < SLICE; ++i) {
            const int a = a0 + i;
            vh += Wh[a * DD + tid] * Wc[a];
            vq += Wq[a * DD + tid] * Wc[DAA + a];
        }
        ws[WS_VHP + blk * DD + tid] = vh;
        ws[WS_VQP + blk * DD + tid] = vq;
    } else {
        if (tid < DPP) {
            float vp1 = 0.f, vp2 = 0.f;
            for (int a = 0; a < DPP; ++a) {
                vp1 += Wp1[a * DPP + tid] * Wc[2 * DAA + a];
                vp2 += Wp2[a * DPP + tid] * Wc[2 * DAA + DPP + a];
            }
            ws[WS_VP + tid]       = vp1;   // lanes 0..31 read pairs from here
            ws[WS_VP + DPP + tid] = vp2;   // lanes 32..63 read pairs from here
        }
        if (tid == 0) ws[WS_BC] = bc[0];
    }
}

// ---------------------------------------------------------------------------
// Kernel 1: streaming tanh-softmax context. tanh(score) in [-1,1] so
// exp(t) in [0.37,2.72] -> plain accumulation, no online max.
// FINAL (R13 = R4/R9 revert): single-buffer BATCH=8, (256,6), CHUNKS=32.
// Verdict from R2-R7: every double-buffer variant (macro/lambda/named-SSA,
// with/without amdgpu_waves_per_eu) regressed 26-40us -- the allocator
// targets 8 waves/EU (VGPR cap 64) and spills the second buffer set
// (76-94MB scratch writeback), and even when occupancy-capped the
// pipeline adds nothing because main is NOT latency-limited: the harness
// reset dirties ~2GB of poison through the 256MB L3, so main's 147MB of
// compulsory reads run against concurrent dirty-line drain (~2x effective
// traffic ~= 294MB ~= 47us at 6.3TB/s). Clean main ~40-45us == that
// drain-adjusted floor. Bulk reads nontemporal (no L2/L3 allocation ->
// no extra eviction pressure). No __threadfence (per-block L2 scans
// cost +370us in the original session).
// ---------------------------------------------------------------------------
__global__ __launch_bounds__(256, 6) void
main_kernel(const float* __restrict__ h,
            const float* __restrict__ q,
            const float* __restrict__ pf1,
            const float* __restrict__ pf2,
            float* __restrict__ ws) {
    const int c    = blockIdx.x;
    const int b    = blockIdx.y;
    const int tid  = threadIdx.x;
    const int wave = tid >> 6;
    const int lane = tid & 63;
    const int ll   = lane & 31;

    // per-lane constants: sum the 8 prep partials (L2-hot)
    f4 vh4 = {0.f, 0.f, 0.f, 0.f};
    f4 vq4 = {0.f, 0.f, 0.f, 0.f};
    #pragma unroll
    for (int k = 0; k < VH_SLICES; ++k) {
        vh4 += ((const f4*)(ws + WS_VHP + k * DD))[lane];
        vq4 += ((const f4*)(ws + WS_VQP + k * DD))[lane];
    }
    const f2 vpl = ((const f2*)(ws + WS_VP))[lane];

    // per-batch q scalar, computed redundantly per wave (cached reads)
    const float4 q4 = ((const float4*)(q + (size_t)b * DD))[lane];
    float qp = q4.x * vq4.x + q4.y * vq4.y + q4.z * vq4.z + q4.w * vq4.w;
    #pragma unroll
    for (int off = 32; off >= 1; off >>= 1) qp += __shfl_xor(qp, off, 64);
    const float qd = qp + ws[WS_BC];

    const int s0 = c * ROWS_PER_BLOCK + wave * ROWS_PER_WAVE;
    const f4*    hbase = (const f4*)(h + (size_t)b * SS * DD);
    const float* pfsel = ((lane < 32) ? pf1 : pf2) + (size_t)b * SS * DPP + 2 * ll;

    float  l = 0.f;
    float4 ctx = make_float4(0.f, 0.f, 0.f, 0.f);

    for (int ib = 0; ib < NBATCH; ++ib) {
        const int sb = s0 + ib * BATCH;
        f4    h4[BATCH];
        f2    pv[BATCH];
        float part[BATCH];
        #pragma unroll
        for (int j = 0; j < BATCH; ++j) {
            const int s = sb + j;
            h4[j] = __builtin_nontemporal_load(hbase + (size_t)s * (DD / 4) + lane);
            pv[j] = __builtin_nontemporal_load((const f2*)(pfsel + (size_t)s * DPP));
        }
        #pragma unroll
        for (int j = 0; j < BATCH; ++j) {
            part[j] = h4[j].x * vh4.x + h4[j].y * vh4.y
                    + h4[j].z * vh4.z + h4[j].w * vh4.w
                    + pv[j].x * vpl.x + pv[j].y * vpl.y;
        }
        // 8 independent butterfly chains, interleaved by the compiler
        #pragma unroll
        for (int off = 32; off >= 1; off >>= 1) {
            #pragma unroll
            for (int j = 0; j < BATCH; ++j)
                part[j] += __shfl_xor(part[j], off, 64);
        }
        #pragma unroll
        for (int j = 0; j < BATCH; ++j) {
            const float score = part[j] + qd;
            const float e2 = __expf(2.f * score);
            const float t  = 1.f - 2.f * __builtin_amdgcn_rcpf(e2 + 1.f); // tanh
            const float w  = __expf(t);                                   // [0.37, 2.72]
            l += w;
            ctx.x += w * h4[j].x;
            ctx.y += w * h4[j].y;
            ctx.z += w * h4[j].z;
            ctx.w += w * h4[j].w;
        }
    }

    // combine the block's 4 waves in LDS, then one plain store per thread
    __shared__ float s_l[WAVES_PER_BLOCK];
    __shared__ float s_ctx[WAVES_PER_BLOCK][DD];
    if (lane == 0) s_l[wave] = l;
    ((float4*)s_ctx[wave])[lane] = ctx;
    __syncthreads();

    const float cd = s_ctx[0][tid] + s_ctx[1][tid] + s_ctx[2][tid] + s_ctx[3][tid];
    float* part_out = ws + WS_PART + (size_t)(b * CHUNKS + c) * PART_STRIDE;
    part_out[1 + tid] = cd;
    if (tid == 0) part_out[0] = s_l[0] + s_l[1] + s_l[2] + s_l[3];
}

// ---------------------------------------------------------------------------
// Kernel 2: merge the CHUNKS partials per batch, scale by 1/(L*S).
// ---------------------------------------------------------------------------
__global__ void finalize_kernel(const float* __restrict__ ws,
                                float* __restrict__ out) {
    const int b   = blockIdx.x;
    const int tid = threadIdx.x; // 256
    __shared__ float s_l[CHUNKS];
    const float* base = ws + WS_PART + (size_t)b * CHUNKS * PART_STRIDE;
    if (tid < CHUNKS) s_l[tid] = base[(size_t)tid * PART_STRIDE];
    __syncthreads();
    float L = 0.f, acc = 0.f;
    #pragma unroll 8
    for (int c = 0; c < CHUNKS; ++c) {
        L   += s_l[c];
        acc += base[(size_t)c * PART_STRIDE + 1 + tid];
    }
    out[b * DD + tid] = acc / (L * (float)SS);
}

extern "C" void kernel_launch(void* const* d_in, const int* in_sizes, int n_in,
                              void* d_out, int out_size, void* d_ws, size_t ws_size,
                              hipStream_t stream) {
    const float* h   = (const float*)d_in[0];
    const float* q   = (const float*)d_in[1];
    const float* pf1 = (const float*)d_in[2];
    const float* pf2 = (const float*)d_in[3];
    const float* Wh  = (const float*)d_in[4];
    const float* Wq  = (const float*)d_in[5];
    const float* Wp1 = (const float*)d_in[6];
    const float* Wp2 = (const float*)d_in[7];
    const float* Wc  = (const float*)d_in[8];
    const float* bc  = (const float*)d_in[9];
    float* out = (float*)d_out;
    float* ws  = (float*)d_ws;

    prep_kernel<<<VH_SLICES + 1, 256, 0, stream>>>(Wh, Wq, Wp1, Wp2, Wc, bc, ws);
    main_kernel<<<dim3(CHUNKS, BB), 256, 0, stream>>>(h, q, pf1, pf2, ws);
    finalize_kernel<<<BB, 256, 0, stream>>>(ws, out);
}